// Round 7
// baseline (833.348 us; speedup 1.0000x reference)
//
#include <hip/hip_runtime.h>

typedef unsigned short u16;
typedef unsigned int   u32;
typedef _Float16 f16x8 __attribute__((ext_vector_type(8)));
typedef float  f32x4  __attribute__((ext_vector_type(4)));
typedef float  f32x2  __attribute__((ext_vector_type(2)));
typedef unsigned short u16x8 __attribute__((ext_vector_type(8)));
typedef unsigned int   u32x2 __attribute__((ext_vector_type(2)));
typedef unsigned int   u32x4 __attribute__((ext_vector_type(4)));

#define PPB 128   // pairs per chunk (8 m-tiles); gather = exactly 1 unit/thread
#define CPB 5     // chunks per block -> 1250 blocks = 4.88/CU (98% balance)

// pack two f32 -> two f16 (RNE via native casts)
__device__ __forceinline__ u32 pkf16(float lo, float hi){
  union { _Float16 h[2]; u32 u; } v;
  v.h[0] = (_Float16)lo; v.h[1] = (_Float16)hi;
  return v.u;
}
// inf-safe tanh: x->+inf: t=inf, rcp=0 -> 1; x->-inf: t=0 -> -1.
__device__ __forceinline__ float tanh_fast(float x){
  float t = __builtin_amdgcn_exp2f(x * 2.885390081777926815f); // e^{2x}
  return __builtin_fmaf(-2.f, __builtin_amdgcn_rcpf(t + 1.f), 1.f);
}

// ------- p1 f32 -> f16 table (6.4 MB, ~L2-resident; halves gather traffic)
__global__ __launch_bounds__(256) void p1_to_f16_k(
    const float* __restrict__ in, u16* __restrict__ out, int n8)
{
  int t = blockIdx.x * 256 + threadIdx.x;
  if (t >= n8) return;
  f32x4 v0 = *(const f32x4*)(in + (size_t)t*8);
  f32x4 v1 = *(const f32x4*)(in + (size_t)t*8 + 4);
  u16x8 o;
  union { _Float16 h; u16 u; } c;
#pragma unroll
  for (int e = 0; e < 4; ++e){ c.h = (_Float16)v0[e]; o[e]   = c.u; }
#pragma unroll
  for (int e = 0; e < 4; ++e){ c.h = (_Float16)v1[e]; o[e+4] = c.u; }
  *(u16x8*)(out + (size_t)t*8) = o;
}

// ------- transpose+downcast->f16: in f32[R][C] -> out f16[C][R]; R,C mult of 64
__global__ __launch_bounds__(256) void transpose_cast_f16_k(
    const float* __restrict__ in, u16* __restrict__ out, int R, int C)
{
  __shared__ u16 tile[64][65];
  const int tx = threadIdx.x & 63;
  const int ty = threadIdx.x >> 6;
  const int c0 = blockIdx.x * 64;
  const int r0 = blockIdx.y * 64;
  union { _Float16 h; u16 u; } c;
#pragma unroll
  for (int rr = 0; rr < 16; ++rr){
    int r = ty + rr * 4;
    c.h = (_Float16)in[(size_t)(r0 + r) * C + c0 + tx];
    tile[r][tx] = c.u;
  }
  __syncthreads();
#pragma unroll
  for (int rr = 0; rr < 16; ++rr){
    int r = ty + rr * 4;
    out[(size_t)(c0 + r) * R + r0 + tx] = tile[tx][r];
  }
}

// ------- W2 f32[256][512] -> w2b f16[8][512][32]: w2b[kk][n][kl] = W2[kk*32+kl][n]
__global__ __launch_bounds__(256) void w2_block_f16_k(
    const float* __restrict__ in, u16* __restrict__ out)
{
  __shared__ float tile[32][65];
  const int kk = blockIdx.x;
  const int n0 = blockIdx.y * 64;
  const int t  = threadIdx.x;
  {
    int r  = t >> 3;
    int c8 = t & 7;
    const float* src = in + (size_t)(kk*32 + r)*512 + n0 + c8*8;
    f32x4 v0 = *(const f32x4*)src;
    f32x4 v1 = *(const f32x4*)(src + 4);
#pragma unroll
    for (int e = 0; e < 4; ++e){
      tile[r][c8*8 + e]     = v0[e];
      tile[r][c8*8 + 4 + e] = v1[e];
    }
  }
  __syncthreads();
  {
    int c = t >> 2, part = t & 3;
    u16x8 o;
    union { _Float16 h; u16 u; } cc;
#pragma unroll
    for (int e = 0; e < 8; ++e){ cc.h = (_Float16)tile[part*8 + e][c]; o[e] = cc.u; }
    *(u16x8*)(out + ((size_t)kk*512 + n0 + c)*32 + part*8) = o;
  }
}

// gather one 8-f16 segment of a p1 row
template<bool USE_H>
__device__ __forceinline__ f16x8 ld_p1row(const float* p1, const u16* p1h,
                                          u32 idx, int seg){
  if constexpr (USE_H){
    union { u16x8 u; f16x8 h; } v;
    v.u = *(const u16x8*)(p1h + (size_t)idx*64 + seg*8);
    return v.h;
  } else {
    const f32x4* s = (const f32x4*)(p1 + (size_t)idx*64 + seg*8);
    f32x4 a = s[0], b = s[1];
    f16x8 r;
#pragma unroll
    for (int e = 0; e < 4; ++e){ r[e] = (_Float16)a[e]; r[e+4] = (_Float16)b[e]; }
    return r;
  }
}

// ---------------- fused PILayer: persistent chunk loop, f16 end-to-end ----------
// Per chunk t (2 barriers):
//   A: issue idx(t+1) [2 regs] | GEMM1(t): sh_inter[cur] @ W1 -> tanh -> sh_h ; bar
//   B: issue f16 row loads(t+1) [8 regs] | GEMM2(t) vs reg-resident W2 -> out
//      | pk_add + ds_write(t+1) -> sh_inter[nxt] ; bar ; swap
// W2 (64 regs/wave, f16) loaded once per CPB chunks. All dtypes f16 (>= bf16
// precision at every conversion; same MFMA rate).
template<bool USE_H>
__global__ __launch_bounds__(1024, 4) void pilayer_kernel(
    const float* __restrict__ p1,     // [N_NODES][64] f32
    const u16* __restrict__ p1h,      // [N_NODES][64] f16
    const int* __restrict__ pair_i,   // [NP]
    const int* __restrict__ pair_j,   // [NP]
    const float* __restrict__ basis,  // [NP][8] f32
    const u16* __restrict__ w1t,      // [256][64] f16
    const u16* __restrict__ w2b,      // [8][512][32] f16 (k-blocked W2^T)
    float* __restrict__ out,          // [NP][64] f32
    int n_pairs)
{
  extern __shared__ __align__(16) u16 smem[];
  u16* sh_h  = smem;                 // [128][256] swizzled = 65536 B
  u16* sh_i0 = smem + PPB * 256;     // [128][64]  swizzled = 16384 B
  u16* sh_i1 = sh_i0 + PPB * 64;     // [128][64]  swizzled = 16384 B

  const int tid  = threadIdx.x;
  const int blk  = blockIdx.x;
  const int lane = tid & 63;
  const int w    = tid >> 6;     // wave 0..15
  const int m16  = lane & 15;
  const int q    = lane >> 4;    // quad 0..3
  const int sw3  = m16 & 7;      // sh_inter chunk swizzle
  const int cw   = (w*2 + (q >> 1)) ^ m16;   // sh_h write chunk (4-bit row-XOR)

  // ---- Persistent W2 fragments (64 regs) + W1 fragments (8 regs) ----
  f16x8 awf[8][2];
#pragma unroll
  for (int kk = 0; kk < 8; ++kk)
#pragma unroll
    for (int nt = 0; nt < 2; ++nt)
      awf[kk][nt] = *(const f16x8*)(
          w2b + ((size_t)kk*512 + w*32 + nt*16 + m16)*32 + q*8);
  const u16* arow = w1t + (size_t)(w*16 + m16)*64 + q*8;
  f16x8 af0 = *(const f16x8*)(arow);
  f16x8 af1 = *(const f16x8*)(arow + 32);
  __builtin_amdgcn_sched_barrier(0);

  const int pbase = blk * CPB * PPB;
  const int m_g   = tid >> 3;          // gather row 0..127 (1 unit/thread)
  const int seg_g = tid & 7;           // 8-f16 segment 0..7

  // ---- Prologue: direct gather of chunk 0 -> sh_i0 ----
  {
    int p = pbase + m_g;
    if (p >= n_pairs) p = n_pairs - 1;
    f16x8 vi = ld_p1row<USE_H>(p1, p1h, (u32)pair_i[p], seg_g);
    f16x8 vj = ld_p1row<USE_H>(p1, p1h, (u32)pair_j[p], seg_g);
    union { f16x8 h; u32x4 u; } sv; sv.h = vi + vj;   // v_pk_add_f16 x4
    *(u32x4*)(sh_i0 + m_g*64 + ((seg_g ^ (m_g & 7)) * 8)) = sv.u;
  }
  __syncthreads();

  u16* sin_cur = sh_i0;
  u16* sin_nxt = sh_i1;

  for (int t = 0; t < CPB; ++t){
    const int pb = pbase + t * PPB;
    const bool pf = (t + 1 < CPB);

    // ---- A: issue next-chunk index loads (2 regs; used at B-top) ----
    int nxt_i = 0, nxt_j = 0;
    if (pf){
      int pn = pb + PPB + m_g;
      if (pn >= n_pairs) pn = n_pairs - 1;
      nxt_i = pair_i[pn];
      nxt_j = pair_j[pn];
    }
    __builtin_amdgcn_sched_barrier(0);   // ordering pin only

    // ---- A: GEMM1 + tanh -> sh_h ----
    for (int mt1 = 0; mt1 < PPB/16; ++mt1){
      const u16* irow = sin_cur + (size_t)(mt1*16 + m16) * 64;
      f16x8 b0 = *(const f16x8*)(irow + ((q ^ sw3) * 8));
      f16x8 b1 = *(const f16x8*)(irow + (((q + 4) ^ sw3) * 8));
      f32x4 acc = {0.f, 0.f, 0.f, 0.f};
      acc = __builtin_amdgcn_mfma_f32_16x16x32_f16(af0, b0, acc, 0, 0, 0);
      acc = __builtin_amdgcn_mfma_f32_16x16x32_f16(af1, b1, acc, 0, 0, 0);
      u32x2 pk;
      pk[0] = pkf16(tanh_fast(acc[0]), tanh_fast(acc[1]));
      pk[1] = pkf16(tanh_fast(acc[2]), tanh_fast(acc[3]));
      *(u32x2*)(sh_h + (size_t)(mt1*16 + m16)*256 + cw*8 + (q & 1)*4) = pk;
    }
    __syncthreads();

    // ---- B: issue next-chunk f16 row loads (8 regs; used at B-end) ----
    f16x8 vi, vj;
    if (pf){
      vi = ld_p1row<USE_H>(p1, p1h, (u32)nxt_i, seg_g);
      vj = ld_p1row<USE_H>(p1, p1h, (u32)nxt_j, seg_g);
    }
    __builtin_amdgcn_sched_barrier(0);   // keep load issue before GEMM2

    // ---- B: GEMM2 vs register W2, fold basis, direct store ----
    for (int mt = 0; mt < PPB/16; ++mt){
      const int row = mt*16 + m16;
      const int mg  = pb + row;
      const int mgc = (mg < n_pairs) ? mg : (n_pairs - 1);
      f32x4 bb = *(const f32x4*)(basis + (size_t)mgc*8 + (q & 1)*4);

      const u16* hbase = sh_h + (size_t)row * 256;
      f32x4 acc0 = {0.f, 0.f, 0.f, 0.f};
      f32x4 acc1 = {0.f, 0.f, 0.f, 0.f};

      f16x8 bh = *(const f16x8*)(hbase + ((q ^ m16) * 8));   // chunk kk=0
#pragma unroll
      for (int kk = 0; kk < 8; ++kk){
        f16x8 bhn;
        if (kk < 7) bhn = *(const f16x8*)(hbase + ((((kk + 1)*4 + q) ^ m16) * 8));
        acc0 = __builtin_amdgcn_mfma_f32_16x16x32_f16(awf[kk][0], bh, acc0, 0, 0, 0);
        acc1 = __builtin_amdgcn_mfma_f32_16x16x32_f16(awf[kk][1], bh, acc1, 0, 0, 0);
        bh = bhn;
      }

      // n = w*32 + nt*16 + q*4 + reg; c = w*4 + nt*2 + (q>>1); b = (q&1)*4 + reg
#pragma unroll
      for (int nt = 0; nt < 2; ++nt){
        f32x4 a = (nt == 0) ? acc0 : acc1;
        float s = a[0]*bb[0] + a[1]*bb[1] + a[2]*bb[2] + a[3]*bb[3];
        s += __shfl_xor(s, 16);          // sum b-halves (q0+q1 / q2+q3)
        float v2 = __shfl_xor(s, 32);    // partner c-channel
        if (q == 0 && mg < n_pairs){
          f32x2 pk = {s, v2};
          *(f32x2*)(out + (size_t)mg*64 + w*4 + nt*2) = pk;
        }
      }
    }

    // ---- B-end: stage chunk t+1 into the other inter buffer ----
    if (pf){
      union { f16x8 h; u32x4 u; } sv; sv.h = vi + vj;
      *(u32x4*)(sin_nxt + m_g*64 + ((seg_g ^ (m_g & 7)) * 8)) = sv.u;
    }
    __syncthreads();
    u16* tmp = sin_cur; sin_cur = sin_nxt; sin_nxt = tmp;
  }
}

extern "C" void kernel_launch(void* const* d_in, const int* in_sizes, int n_in,
                              void* d_out, int out_size, void* d_ws, size_t ws_size,
                              hipStream_t stream)
{
  const float* p1    = (const float*)d_in[0];
  const int*   pi    = (const int*)d_in[1];
  const int*   pj    = (const int*)d_in[2];
  const float* basis = (const float*)d_in[3];
  const float* W1    = (const float*)d_in[4];  // [64][256] f32
  const float* W2    = (const float*)d_in[5];  // [256][512] f32
  float* out = (float*)d_out;

  const int n_pairs = in_sizes[1];
  const int n_nodes = in_sizes[0] / 64;        // p1 floats / 64

  u16* w1t = (u16*)d_ws;                       // [256][64]    f16 = 32 KB
  u16* w2b = w1t + 64 * 256;                   // [8][512][32] f16 = 256 KB
  u16* p1h = w2b + 8 * 512 * 32;               // [n_nodes][64] f16 = 6.4 MB
  const size_t need = (size_t)(64*256 + 8*512*32 + (size_t)n_nodes*64) * sizeof(u16);
  const bool use_h = (ws_size >= need);

  const int lds_bytes = (PPB * 256 + 2 * PPB * 64) * (int)sizeof(u16);  // 98304

  static int attr_done = 0;  // device-global state; set before graph capture
  if (!attr_done){
    hipFuncSetAttribute((const void*)pilayer_kernel<true>,
                        hipFuncAttributeMaxDynamicSharedMemorySize, lds_bytes);
    hipFuncSetAttribute((const void*)pilayer_kernel<false>,
                        hipFuncAttributeMaxDynamicSharedMemorySize, lds_bytes);
    attr_done = 1;
  }

  transpose_cast_f16_k<<<dim3(4, 1), 256, 0, stream>>>(W1, w1t, 64, 256);
  w2_block_f16_k<<<dim3(8, 8), 256, 0, stream>>>(W2, w2b);
  if (use_h){
    const int n8 = n_nodes * 8;                // 16B units
    p1_to_f16_k<<<(n8 + 255)/256, 256, 0, stream>>>(p1, p1h, n8);
  }

  const int n_chunks = (n_pairs + PPB - 1) / PPB;
  const int blocks   = (n_chunks + CPB - 1) / CPB;
  if (use_h)
    pilayer_kernel<true><<<blocks, 1024, lds_bytes, stream>>>(
        p1, p1h, pi, pj, basis, w1t, w2b, out, n_pairs);
  else
    pilayer_kernel<false><<<blocks, 1024, lds_bytes, stream>>>(
        p1, nullptr, pi, pj, basis, w1t, w2b, out, n_pairs);
}